// Round 6
// baseline (97.296 us; speedup 1.0000x reference)
//
#include <hip/hip_runtime.h>
#include <math.h>
#include <limits.h>

// Problem constants (fixed by reference setup_inputs)
constexpr int N = 8;
constexpr int H = 256;
constexpr int W = 256;
constexpr int NPIX = N * H * W;          // 524288
constexpr float FEPS = 1e-6f;
constexpr int   NBLK = N * H;            // 2048 blocks, one per (image,row)
constexpr int   HBIG = 20000;            // "no bit in row" sentinel; HBIG^2 = 4e8 >> 130050
constexpr int   EMPTY_THRESH = 300000000;// > legit max 130050, < HBIG^2

// ws layout:
//   float    parts[5][NBLK]  : q=0: p*t, 1: p, 2: t, 3: phi*p, 4: focal
//   unsigned flags[NBLK]     : release flags (written before read each call;
//                              any init != 1 is safe — harness poisons 0xAA)

__global__ __launch_bounds__(256) void fused_kernel(
    const float* __restrict__ pred, const float* __restrict__ tgt,
    float* __restrict__ parts, unsigned int* __restrict__ flags,
    float* __restrict__ out)
{
    const int blk  = blockIdx.x;             // n*H + py
    const int n    = blk >> 8;
    const int py   = blk & 255;
    const int px   = threadIdx.x;
    const int lane = px & 63;
    const int w    = px >> 6;                // own 64-bit word index (wave-uniform)

    // 256-bit fg/bg occupancy masks for the 7 window rows (invalid rows -> 0 in BOTH)
    __shared__ unsigned long long mrow[7][4][2];   // [row][word][0=fg,1=bg]

    const float x = pred[blk * W + px];
    float t = 0.0f;

    #pragma unroll
    for (int r = 0; r < 7; ++r) {
        const int qy = py + r - 3;
        const bool valid = (qy >= 0) && (qy < H);          // block-uniform
        float tv = 0.0f;
        if (valid) tv = tgt[(n * H + qy) * W + px];
        if (r == 3) t = tv;                                // own row target
        const bool fgb = valid && (tv > 0.5f);
        const bool bgb = valid && !(tv > 0.5f);
        const unsigned long long bf = __ballot(fgb);
        const unsigned long long bb = __ballot(bgb);
        if (lane == 0) { mrow[r][w][0] = bf; mrow[r][w][1] = bb; }
    }
    __syncthreads();

    // Exact EDT over |dy|<=3: best = min_d ( d^2 + hdist(row[py-d]|row[py+d], px)^2 )
    int best_f = INT_MAX, best_b = INT_MAX;
    #pragma unroll
    for (int d = 0; d <= 3; ++d) {
        #pragma unroll
        for (int ty = 0; ty < 2; ++ty) {
            int h = HBIG;
            #pragma unroll
            for (int ww = 0; ww < 4; ++ww) {
                const unsigned long long mm =
                    mrow[3 + d][ww][ty] | mrow[3 - d][ww][ty];
                if (ww == w) {
                    // bits at/above px: lowest set bit of (mm >> lane)
                    const unsigned long long hi = mm >> lane;
                    if (hi) h = min(h, (int)__builtin_ctzll(hi));
                    // bits at/below px: highest set bit of (mm << (63-lane))
                    const unsigned long long lo = mm << (63 - lane);
                    if (lo) h = min(h, (int)__builtin_clzll(lo));
                } else if (mm) {                            // wave-uniform branch
                    int cand;
                    if (ww > w) cand = ww * 64 + (int)__builtin_ctzll(mm) - px;
                    else        cand = px - (ww * 64 + 63 - (int)__builtin_clzll(mm));
                    h = min(h, cand);
                }
            }
            const int v = d * d + h * h;
            if (ty == 0) best_f = min(best_f, v);
            else         best_b = min(best_b, v);
        }
    }

    // Rare exact fallback beyond the window: rows at |dy|=dlt contribute >= dlt^2,
    // so stop once dlt^2 >= best for every lane. Brute-scans whole rows (exact).
    for (int dlt = 4; dlt < H; ++dlt) {
        const int d2 = dlt * dlt;
        if (!__any((d2 < best_f) || (d2 < best_b))) break;
        #pragma unroll
        for (int s = 0; s < 2; ++s) {
            const int qy = s ? (py + dlt) : (py - dlt);
            if (qy < 0 || qy >= H) continue;               // block-uniform
            const float* __restrict__ row = tgt + (size_t)(n * H + qy) * W;
            for (int qx = 0; qx < W; ++qx) {
                const float tv = row[qx];                  // broadcast load
                const int dx = px - qx;
                const int dd = d2 + dx * dx;
                if (tv > 0.5f) best_f = min(best_f, dd);
                else           best_b = min(best_b, dd);
            }
        }
    }

    const float MAXD2 = (float)((H - 1) * (H - 1) + (W - 1) * (W - 1));
    const float Dfg = (best_f > EMPTY_THRESH) ? MAXD2 : (float)best_f;  // image-empty fallback
    const float Dbg = (best_b > EMPTY_THRESH) ? MAXD2 : (float)best_b;

    const float p   = 1.0f / (1.0f + expf(-x));
    const float phi = (t > 0.5f) ? -sqrtf(Dbg) : sqrtf(Dfg);

    const float pc = fminf(fmaxf(p, FEPS), 1.0f - FEPS);
    const float pt = pc * t + (1.0f - pc) * (1.0f - t);
    const float at = 0.25f * t + 0.75f * (1.0f - t);
    const float om = 1.0f - pt;
    const float focal = -at * om * om * logf(pt);

    // block reduction of the 5 partials
    float v5[5] = { p * t, p, t, phi * p, focal };
    __shared__ float smem[4 * 5];
    #pragma unroll
    for (int q = 0; q < 5; ++q) {
        float v = v5[q];
        #pragma unroll
        for (int off = 32; off > 0; off >>= 1) v += __shfl_down(v, off, 64);
        v5[q] = v;
    }
    if (lane == 0) {
        #pragma unroll
        for (int q = 0; q < 5; ++q) smem[w * 5 + q] = v5[q];
    }
    __syncthreads();
    if (threadIdx.x == 0) {
        #pragma unroll
        for (int q = 0; q < 5; ++q) {
            parts[q * NBLK + blk] = smem[q] + smem[5 + q] + smem[10 + q] + smem[15 + q];
        }
        // release: parts visible device-wide before the flag
        __hip_atomic_store(&flags[blk], 1u, __ATOMIC_RELEASE, __HIP_MEMORY_SCOPE_AGENT);
    }

    if (blk != 0) return;

    // ---- block 0: wait for all blocks' partials, then finalize ----
    for (int k = threadIdx.x; k < NBLK; k += 256) {
        while (__hip_atomic_load(&flags[k], __ATOMIC_ACQUIRE,
                                 __HIP_MEMORY_SCOPE_AGENT) != 1u) {
            __builtin_amdgcn_s_sleep(1);
        }
    }
    __threadfence();
    __syncthreads();

    const int tid  = threadIdx.x;
    const int wid  = tid >> 6;
    __shared__ float smf[8];
    __shared__ float sratio[8];

    // boundary + focal: global sums over all NBLK partials
    float bp = 0.0f, fc = 0.0f;
    for (int k = tid; k < NBLK; k += 256) {
        bp += parts[3 * NBLK + k];
        fc += parts[4 * NBLK + k];
    }
    #pragma unroll
    for (int off = 32; off > 0; off >>= 1) {
        bp += __shfl_down(bp, off, 64);
        fc += __shfl_down(fc, off, 64);
    }
    if (lane == 0) { smf[wid * 2] = bp; smf[wid * 2 + 1] = fc; }

    // dice: each wave handles 2 images (256 partials each)
    #pragma unroll
    for (int mi = 0; mi < 2; ++mi) {
        const int m = wid * 2 + mi;
        float A = 0.f, S = 0.f, C = 0.f;
        #pragma unroll
        for (int k = 0; k < 4; ++k) {
            const int i = m * 256 + k * 64 + lane;
            A += parts[0 * NBLK + i];
            S += parts[1 * NBLK + i];
            C += parts[2 * NBLK + i];
        }
        #pragma unroll
        for (int off = 32; off > 0; off >>= 1) {
            A += __shfl_down(A, off, 64);
            S += __shfl_down(S, off, 64);
            C += __shfl_down(C, off, 64);
        }
        if (lane == 0) sratio[m] = (2.0f * A + FEPS) / (S + C + FEPS);
    }
    __syncthreads();
    if (tid == 0) {
        const float B = smf[0] + smf[2] + smf[4] + smf[6];
        const float F = smf[1] + smf[3] + smf[5] + smf[7];
        float dacc = 0.0f;
        #pragma unroll
        for (int m = 0; m < 8; ++m) dacc += sratio[m];
        const float dice_val     = 1.0f - dacc / (float)N;
        const float boundary_val = B / (float)NPIX;
        const float focal_val    = F / (float)NPIX;
        out[0] = dice_val + boundary_val + focal_val;   // loss
        out[1] = dice_val;
        out[2] = boundary_val;
        out[3] = focal_val;
    }
}

extern "C" void kernel_launch(void* const* d_in, const int* in_sizes, int n_in,
                              void* d_out, int out_size, void* d_ws, size_t ws_size,
                              hipStream_t stream)
{
    const float* pred = (const float*)d_in[0];
    const float* tgt  = (const float*)d_in[1];
    float* out = (float*)d_out;

    float*        parts = (float*)d_ws;                  // 5 * 2048 floats
    unsigned int* flags = (unsigned int*)(parts + 5 * NBLK);

    fused_kernel<<<NBLK, 256, 0, stream>>>(pred, tgt, parts, flags, out);
}

// Round 7
// 74.581 us; speedup vs baseline: 1.3046x; 1.3046x over previous
//
#include <hip/hip_runtime.h>
#include <math.h>
#include <limits.h>

// Problem constants (fixed by reference setup_inputs)
constexpr int N = 8;
constexpr int H = 256;
constexpr int W = 256;
constexpr int NPIX = N * H * W;          // 524288
constexpr float FEPS = 1e-6f;
constexpr int   NBLK = N * H;            // 2048 blocks, one per (image,row)
constexpr int   HBIG = 20000;            // "no bit in row" sentinel; HBIG^2 = 4e8 >> 130050
constexpr int   EMPTY_THRESH = 300000000;// > legit max 130050, < HBIG^2

// ws layout:
//   float parts[5][NBLK] : q=0: p*t, 1: p, 2: t, 3: phi*p, 4: focal
// (no flags, no counters — cross-block sync via separate dispatch; in-kernel
//  agent-scope release/acquire measured 3x slower than a 1-block finalize)

// -------- Kernel 1: ballot-window exact EDT + loss terms + block reduce --------
__global__ __launch_bounds__(256) void main_kernel(
    const float* __restrict__ pred, const float* __restrict__ tgt,
    float* __restrict__ parts)
{
    const int blk  = blockIdx.x;             // n*H + py
    const int n    = blk >> 8;
    const int py   = blk & 255;
    const int px   = threadIdx.x;
    const int lane = px & 63;
    const int w    = px >> 6;                // own 64-bit word index (wave-uniform)

    // 256-bit fg/bg occupancy masks for the 7 window rows (invalid rows -> 0 in BOTH)
    __shared__ unsigned long long mrow[7][4][2];   // [row][word][0=fg,1=bg]

    const float x = pred[blk * W + px];
    float t = 0.0f;

    #pragma unroll
    for (int r = 0; r < 7; ++r) {
        const int qy = py + r - 3;
        const bool valid = (qy >= 0) && (qy < H);          // block-uniform
        float tv = 0.0f;
        if (valid) tv = tgt[(n * H + qy) * W + px];
        if (r == 3) t = tv;                                // own row target
        const bool fgb = valid && (tv > 0.5f);
        const bool bgb = valid && !(tv > 0.5f);
        const unsigned long long bf = __ballot(fgb);
        const unsigned long long bb = __ballot(bgb);
        if (lane == 0) { mrow[r][w][0] = bf; mrow[r][w][1] = bb; }
    }
    __syncthreads();

    // Exact EDT over |dy|<=3: best = min_d ( d^2 + hdist(row[py-d]|row[py+d], px)^2 )
    int best_f = INT_MAX, best_b = INT_MAX;
    #pragma unroll
    for (int d = 0; d <= 3; ++d) {
        #pragma unroll
        for (int ty = 0; ty < 2; ++ty) {
            int h = HBIG;
            #pragma unroll
            for (int ww = 0; ww < 4; ++ww) {
                const unsigned long long mm =
                    mrow[3 + d][ww][ty] | mrow[3 - d][ww][ty];
                if (ww == w) {
                    // bits at/above px: lowest set bit of (mm >> lane)
                    const unsigned long long hi = mm >> lane;
                    if (hi) h = min(h, (int)__builtin_ctzll(hi));
                    // bits at/below px: highest set bit of (mm << (63-lane))
                    const unsigned long long lo = mm << (63 - lane);
                    if (lo) h = min(h, (int)__builtin_clzll(lo));
                } else if (mm) {                            // wave-uniform branch
                    int cand;
                    if (ww > w) cand = ww * 64 + (int)__builtin_ctzll(mm) - px;
                    else        cand = px - (ww * 64 + 63 - (int)__builtin_clzll(mm));
                    h = min(h, cand);
                }
            }
            const int v = d * d + h * h;
            if (ty == 0) best_f = min(best_f, v);
            else         best_b = min(best_b, v);
        }
    }

    // Rare exact fallback beyond the window: rows at |dy|=dlt contribute >= dlt^2,
    // so stop once dlt^2 >= best for every lane. Brute-scans whole rows (exact).
    for (int dlt = 4; dlt < H; ++dlt) {
        const int d2 = dlt * dlt;
        if (!__any((d2 < best_f) || (d2 < best_b))) break;
        #pragma unroll
        for (int s = 0; s < 2; ++s) {
            const int qy = s ? (py + dlt) : (py - dlt);
            if (qy < 0 || qy >= H) continue;               // block-uniform
            const float* __restrict__ row = tgt + (size_t)(n * H + qy) * W;
            for (int qx = 0; qx < W; ++qx) {
                const float tv = row[qx];                  // broadcast load
                const int dx = px - qx;
                const int dd = d2 + dx * dx;
                if (tv > 0.5f) best_f = min(best_f, dd);
                else           best_b = min(best_b, dd);
            }
        }
    }

    const float MAXD2 = (float)((H - 1) * (H - 1) + (W - 1) * (W - 1));
    const float Dfg = (best_f > EMPTY_THRESH) ? MAXD2 : (float)best_f;  // image-empty fallback
    const float Dbg = (best_b > EMPTY_THRESH) ? MAXD2 : (float)best_b;

    const float p   = 1.0f / (1.0f + expf(-x));
    const float phi = (t > 0.5f) ? -sqrtf(Dbg) : sqrtf(Dfg);

    const float pc = fminf(fmaxf(p, FEPS), 1.0f - FEPS);
    const float pt = pc * t + (1.0f - pc) * (1.0f - t);
    const float at = 0.25f * t + 0.75f * (1.0f - t);
    const float om = 1.0f - pt;
    const float focal = -at * om * om * logf(pt);

    // block reduction of the 5 partials
    float v5[5] = { p * t, p, t, phi * p, focal };
    __shared__ float smem[4 * 5];
    #pragma unroll
    for (int q = 0; q < 5; ++q) {
        float v = v5[q];
        #pragma unroll
        for (int off = 32; off > 0; off >>= 1) v += __shfl_down(v, off, 64);
        v5[q] = v;
    }
    if (lane == 0) {
        #pragma unroll
        for (int q = 0; q < 5; ++q) smem[w * 5 + q] = v5[q];
    }
    __syncthreads();
    if (threadIdx.x == 0) {
        #pragma unroll
        for (int q = 0; q < 5; ++q) {
            parts[q * NBLK + blk] = smem[q] + smem[5 + q] + smem[10 + q] + smem[15 + q];
        }
    }
}

// -------- Kernel 2: final reduction to the 4 scalars --------
__global__ __launch_bounds__(256) void finalize_kernel(
    const float* __restrict__ parts, float* __restrict__ out)
{
    const int tid  = threadIdx.x;        // 256 threads
    const int lane = tid & 63;
    const int wid  = tid >> 6;
    __shared__ float smf[8];
    __shared__ float sratio[8];

    // boundary + focal: global sums over all NBLK partials
    float bp = 0.0f, fc = 0.0f;
    for (int k = tid; k < NBLK; k += 256) {
        bp += parts[3 * NBLK + k];
        fc += parts[4 * NBLK + k];
    }
    #pragma unroll
    for (int off = 32; off > 0; off >>= 1) {
        bp += __shfl_down(bp, off, 64);
        fc += __shfl_down(fc, off, 64);
    }
    if (lane == 0) { smf[wid * 2] = bp; smf[wid * 2 + 1] = fc; }

    // dice: each wave handles 2 images (256 partials each)
    #pragma unroll
    for (int mi = 0; mi < 2; ++mi) {
        const int m = wid * 2 + mi;
        float A = 0.f, S = 0.f, C = 0.f;
        #pragma unroll
        for (int k = 0; k < 4; ++k) {
            const int i = m * 256 + k * 64 + lane;
            A += parts[0 * NBLK + i];
            S += parts[1 * NBLK + i];
            C += parts[2 * NBLK + i];
        }
        #pragma unroll
        for (int off = 32; off > 0; off >>= 1) {
            A += __shfl_down(A, off, 64);
            S += __shfl_down(S, off, 64);
            C += __shfl_down(C, off, 64);
        }
        if (lane == 0) sratio[m] = (2.0f * A + FEPS) / (S + C + FEPS);
    }
    __syncthreads();
    if (tid == 0) {
        const float B = smf[0] + smf[2] + smf[4] + smf[6];
        const float F = smf[1] + smf[3] + smf[5] + smf[7];
        float dacc = 0.0f;
        #pragma unroll
        for (int m = 0; m < 8; ++m) dacc += sratio[m];
        const float dice_val     = 1.0f - dacc / (float)N;
        const float boundary_val = B / (float)NPIX;
        const float focal_val    = F / (float)NPIX;
        out[0] = dice_val + boundary_val + focal_val;   // loss
        out[1] = dice_val;
        out[2] = boundary_val;
        out[3] = focal_val;
    }
}

extern "C" void kernel_launch(void* const* d_in, const int* in_sizes, int n_in,
                              void* d_out, int out_size, void* d_ws, size_t ws_size,
                              hipStream_t stream)
{
    const float* pred = (const float*)d_in[0];
    const float* tgt  = (const float*)d_in[1];
    float* out = (float*)d_out;

    float* parts = (float*)d_ws;                  // 5 * 2048 floats

    main_kernel<<<NBLK, 256, 0, stream>>>(pred, tgt, parts);
    finalize_kernel<<<1, 256, 0, stream>>>(parts, out);
}